// Round 1
// baseline (114793.152 us; speedup 1.0000x reference)
//
#include <hip/hip_runtime.h>
#include <hip/hip_bf16.h>

// ---- problem constants ----
#define NB   1024      // batch
#define TT   64        // timesteps
#define DXL  300
#define DXA  74
#define DXV  35
#define DX   (DXL+DXA+DXV)   // 409
#define DHL  512
#define DHA  256
#define DHV  256
#define TOTH 1024      // DHL+DHA+DHV
#define MEMD 512
#define HMLP 1024
#define ATTIN 2048     // 2*TOTH
#define GAMIN 2560     // ATTIN+MEMD
#define FINAL_IN 1536  // TOTH+MEMD

// ---------------------------------------------------------------------------
// Generic fp32 NT GEMM: C[m][n] = act( sum_k A[m][k]*W[n][k] + bias(n) )
// A is a 2-part composite: k<K0 -> A0[m*lda0+k], else A1[m*lda1+(k-K0)]
// W is a 2-part composite: k<K0 -> W0[n*ldw0+k], else W1[n*ldw1+(k-K0)]
// bias = bias0[n] (+ bias1[n] if non-null)
// Tile: 64x64 output, BK=16, 256 threads, 4x4 per thread.
// Requires M%64==0 && Nout%64==0 (true for all call sites here).
// ---------------------------------------------------------------------------
template<int ACT>   // 0=none 1=relu 2=sigmoid 3=tanh
__global__ __launch_bounds__(256) void gemm_nt(
    const float* __restrict__ A0, int lda0, int K0,
    const float* __restrict__ A1, int lda1, int K1,
    const float* __restrict__ W0, int ldw0,
    const float* __restrict__ W1, int ldw1,
    const float* __restrict__ bias0, const float* __restrict__ bias1,
    float* __restrict__ C, int ldc)
{
    const int K = K0 + K1;
    __shared__ float As[16][65];   // [k][m], +1 pad to avoid store conflicts
    __shared__ float Ws[16][65];   // [k][n]
    const int tid = threadIdx.x;
    const int bm = blockIdx.y * 64;
    const int bn = blockIdx.x * 64;
    const int tx = tid & 15;       // n-tile index
    const int ty = tid >> 4;       // m-tile index

    float acc[4][4] = {};

    for (int k0 = 0; k0 < K; k0 += 16) {
        #pragma unroll
        for (int i = 0; i < 4; ++i) {
            int e  = tid + 256 * i;       // 0..1023
            int m  = e >> 4;              // 0..63
            int kk = e & 15;              // 0..15
            int kg = k0 + kk;
            float va = 0.f, vw = 0.f;
            if (kg < K0)      va = A0[(size_t)(bm + m) * lda0 + kg];
            else if (kg < K)  va = A1[(size_t)(bm + m) * lda1 + (kg - K0)];
            if (kg < K0)      vw = W0[(size_t)(bn + m) * ldw0 + kg];
            else if (kg < K)  vw = W1[(size_t)(bn + m) * ldw1 + (kg - K0)];
            As[kk][m] = va;
            Ws[kk][m] = vw;
        }
        __syncthreads();
        #pragma unroll
        for (int kk = 0; kk < 16; ++kk) {
            float a[4], b[4];
            #pragma unroll
            for (int i = 0; i < 4; ++i) a[i] = As[kk][ty * 4 + i];
            #pragma unroll
            for (int j = 0; j < 4; ++j) b[j] = Ws[kk][tx * 4 + j];
            #pragma unroll
            for (int i = 0; i < 4; ++i)
                #pragma unroll
                for (int j = 0; j < 4; ++j)
                    acc[i][j] += a[i] * b[j];
        }
        __syncthreads();
    }

    #pragma unroll
    for (int i = 0; i < 4; ++i) {
        int row = bm + ty * 4 + i;
        #pragma unroll
        for (int j = 0; j < 4; ++j) {
            int col = bn + tx * 4 + j;
            float v = acc[i][j] + bias0[col];
            if (bias1) v += bias1[col];
            if (ACT == 1) v = fmaxf(v, 0.f);
            else if (ACT == 2) v = 1.f / (1.f + __expf(-v));
            else if (ACT == 3) v = tanhf(v);
            C[(size_t)row * ldc + col] = v;
        }
    }
}

// ---------------------------------------------------------------------------
// LSTM pointwise for all 3 modalities.
// hs/cs rows are laid out [L(512) | A(256) | V(256)] (1024 per batch row).
// gates buffers: gl (N,2048), ga (N,1024), gv (N,1024); order i,f,g,o.
// ---------------------------------------------------------------------------
__global__ void lstm_pointwise(const float* __restrict__ gl,
                               const float* __restrict__ ga,
                               const float* __restrict__ gv,
                               const float* __restrict__ cs_prev,
                               float* __restrict__ cs_new,
                               float* __restrict__ hs_new)
{
    int idx = blockIdx.x * blockDim.x + threadIdx.x;   // N*1024
    if (idx >= NB * TOTH) return;
    int n = idx >> 10, u = idx & 1023;
    const float* g; int dh, gu;
    if (u < DHL)            { g = gl; dh = DHL; gu = u; }
    else if (u < DHL + DHA) { g = ga; dh = DHA; gu = u - DHL; }
    else                    { g = gv; dh = DHV; gu = u - DHL - DHA; }
    const float* grow = g + (size_t)n * 4 * dh;
    float gi = grow[gu], gf = grow[dh + gu], gg = grow[2 * dh + gu], go = grow[3 * dh + gu];
    float c  = cs_prev[idx];
    float si = 1.f / (1.f + __expf(-gi));
    float sf = 1.f / (1.f + __expf(-gf));
    float so = 1.f / (1.f + __expf(-go));
    float c2 = sf * c + si * tanhf(gg);
    cs_new[idx] = c2;
    hs_new[idx] = so * tanhf(c2);
}

// ---------------------------------------------------------------------------
// Row softmax over 2048 logits, then attended = softmax * cStar,
// cStar = [cs_prev | cs_new]. One block (256 thr) per batch row.
// ---------------------------------------------------------------------------
__global__ __launch_bounds__(256) void softmax_attend(
    const float* __restrict__ logits,
    const float* __restrict__ cs_prev,
    const float* __restrict__ cs_new,
    float* __restrict__ attended)
{
    int n = blockIdx.x;
    const float* z = logits + (size_t)n * ATTIN;
    __shared__ float sred[4];
    int tid = threadIdx.x, lane = tid & 63, wid = tid >> 6;

    float m = -1e30f;
    for (int k = tid; k < ATTIN; k += 256) m = fmaxf(m, z[k]);
    #pragma unroll
    for (int off = 1; off < 64; off <<= 1) m = fmaxf(m, __shfl_xor(m, off));
    if (lane == 0) sred[wid] = m;
    __syncthreads();
    m = fmaxf(fmaxf(sred[0], sred[1]), fmaxf(sred[2], sred[3]));
    __syncthreads();

    float s = 0.f;
    for (int k = tid; k < ATTIN; k += 256) s += __expf(z[k] - m);
    #pragma unroll
    for (int off = 1; off < 64; off <<= 1) s += __shfl_xor(s, off);
    if (lane == 0) sred[wid] = s;
    __syncthreads();
    s = sred[0] + sred[1] + sred[2] + sred[3];
    float inv = 1.f / s;

    for (int k = tid; k < ATTIN; k += 256) {
        float cs = (k < TOTH) ? cs_prev[(size_t)n * TOTH + k]
                              : cs_new[(size_t)n * TOTH + (k - TOTH)];
        attended[(size_t)n * ATTIN + k] = __expf(z[k] - m) * inv * cs;
    }
}

// mem = gamma1*mem + gamma2*cHat (elementwise, in place)
__global__ void mem_update(float* __restrict__ memb,
                           const float* __restrict__ g1,
                           const float* __restrict__ g2,
                           const float* __restrict__ chat)
{
    int idx = blockIdx.x * blockDim.x + threadIdx.x;
    if (idx >= NB * MEMD) return;
    memb[idx] = g1[idx] * memb[idx] + g2[idx] * chat[idx];
}

// out[n] = dot(hid[n], w2) + b2, hid (N,1024), w2 (1024). 1 wave per row.
__global__ __launch_bounds__(256) void out_dot(const float* __restrict__ hid,
                                               const float* __restrict__ w2,
                                               const float* __restrict__ b2,
                                               float* __restrict__ out)
{
    int wid = threadIdx.x >> 6, lane = threadIdx.x & 63;
    int n = blockIdx.x * 4 + wid;
    if (n >= NB) return;
    const float* h = hid + (size_t)n * HMLP;
    float s = 0.f;
    for (int k = lane; k < HMLP; k += 64) s += h[k] * w2[k];
    #pragma unroll
    for (int off = 1; off < 64; off <<= 1) s += __shfl_xor(s, off);
    if (lane == 0) out[n] = s + b2[0];
}

__global__ void zero_fill(float* __restrict__ p, int count)
{
    int idx = blockIdx.x * blockDim.x + threadIdx.x;
    if (idx < count) p[idx] = 0.f;
}

// ---------------------------------------------------------------------------
// host side
// ---------------------------------------------------------------------------
static void gemm(hipStream_t s, int act, int M, int Nout,
                 const float* A0, int lda0, int K0,
                 const float* A1, int lda1, int K1,
                 const float* W0, int ldw0,
                 const float* W1, int ldw1,
                 const float* b0, const float* b1,
                 float* C, int ldc)
{
    dim3 grid(Nout / 64, M / 64), block(256);
    switch (act) {
    case 0: gemm_nt<0><<<grid, block, 0, s>>>(A0, lda0, K0, A1, lda1, K1, W0, ldw0, W1, ldw1, b0, b1, C, ldc); break;
    case 1: gemm_nt<1><<<grid, block, 0, s>>>(A0, lda0, K0, A1, lda1, K1, W0, ldw0, W1, ldw1, b0, b1, C, ldc); break;
    case 2: gemm_nt<2><<<grid, block, 0, s>>>(A0, lda0, K0, A1, lda1, K1, W0, ldw0, W1, ldw1, b0, b1, C, ldc); break;
    case 3: gemm_nt<3><<<grid, block, 0, s>>>(A0, lda0, K0, A1, lda1, K1, W0, ldw0, W1, ldw1, b0, b1, C, ldc); break;
    }
}

extern "C" void kernel_launch(void* const* d_in, const int* in_sizes, int n_in,
                              void* d_out, int out_size, void* d_ws, size_t ws_size,
                              hipStream_t stream)
{
    const float* X      = (const float*)d_in[0];
    const float* Wih_l  = (const float*)d_in[5];
    const float* Whh_l  = (const float*)d_in[6];
    const float* bih_l  = (const float*)d_in[7];
    const float* bhh_l  = (const float*)d_in[8];
    const float* Wih_a  = (const float*)d_in[9];
    const float* Whh_a  = (const float*)d_in[10];
    const float* bih_a  = (const float*)d_in[11];
    const float* bhh_a  = (const float*)d_in[12];
    const float* Wih_v  = (const float*)d_in[13];
    const float* Whh_v  = (const float*)d_in[14];
    const float* bih_v  = (const float*)d_in[15];
    const float* bhh_v  = (const float*)d_in[16];
    const float* a1w1   = (const float*)d_in[17];
    const float* a1b1   = (const float*)d_in[18];
    const float* a1w2   = (const float*)d_in[19];
    const float* a1b2   = (const float*)d_in[20];
    const float* a2w1   = (const float*)d_in[21];
    const float* a2b1   = (const float*)d_in[22];
    const float* a2w2   = (const float*)d_in[23];
    const float* a2b2   = (const float*)d_in[24];
    const float* g1w1   = (const float*)d_in[25];
    const float* g1b1   = (const float*)d_in[26];
    const float* g1w2   = (const float*)d_in[27];
    const float* g1b2   = (const float*)d_in[28];
    const float* g2w1   = (const float*)d_in[29];
    const float* g2b1   = (const float*)d_in[30];
    const float* g2w2   = (const float*)d_in[31];
    const float* g2b2   = (const float*)d_in[32];
    const float* ow1    = (const float*)d_in[33];
    const float* ob1    = (const float*)d_in[34];
    const float* ow2    = (const float*)d_in[35];
    const float* ob2    = (const float*)d_in[36];
    float* out = (float*)d_out;

    // workspace carve (floats). hs0, cs0, mem first so one zero_fill covers them.
    float* w = (float*)d_ws;
    float* hs0  = w; w += NB * TOTH;
    float* cs0  = w; w += NB * TOTH;
    float* memb = w; w += NB * MEMD;
    float* hs1  = w; w += NB * TOTH;
    float* cs1  = w; w += NB * TOTH;
    float* gl   = w; w += NB * 4 * DHL;
    float* ga   = w; w += NB * 4 * DHA;
    float* gv   = w; w += NB * 4 * DHV;
    float* hid1 = w; w += NB * HMLP;
    float* lgts = w; w += NB * ATTIN;
    float* attd = w; w += NB * ATTIN;
    float* hid2 = w; w += NB * HMLP;
    float* chat = w; w += NB * MEMD;
    float* hg1  = w; w += NB * HMLP;
    float* hg2  = w; w += NB * HMLP;
    float* gm1  = w; w += NB * MEMD;
    float* gm2  = w; w += NB * MEMD;
    float* hout = w; w += NB * HMLP;

    // zero state (reference starts carry at zeros; priors are ignored by ref)
    {
        int cnt = NB * TOTH * 2 + NB * MEMD;
        zero_fill<<<(cnt + 255) / 256, 256, 0, stream>>>(hs0, cnt);
    }

    float* hsbuf[2] = { hs0, hs1 };
    float* csbuf[2] = { cs0, cs1 };

    for (int t = 0; t < TT; ++t) {
        const float* xt = X + (size_t)t * NB * DX;
        float* hsP = hsbuf[t & 1];
        float* hsN = hsbuf[(t + 1) & 1];
        float* csP = csbuf[t & 1];
        float* csN = csbuf[(t + 1) & 1];

        // LSTM gate GEMMs: gates = [x_t | h] @ [Wih|Whh]^T + bih + bhh
        gemm(stream, 0, NB, 4 * DHL, xt,        DX, DXL, hsP,        TOTH, DHL,
             Wih_l, DXL, Whh_l, DHL, bih_l, bhh_l, gl, 4 * DHL);
        gemm(stream, 0, NB, 4 * DHA, xt + DXL,  DX, DXA, hsP + DHL,  TOTH, DHA,
             Wih_a, DXA, Whh_a, DHA, bih_a, bhh_a, ga, 4 * DHA);
        gemm(stream, 0, NB, 4 * DHV, xt + DXL + DXA, DX, DXV, hsP + DHL + DHA, TOTH, DHV,
             Wih_v, DXV, Whh_v, DHV, bih_v, bhh_v, gv, 4 * DHV);

        lstm_pointwise<<<(NB * TOTH + 255) / 256, 256, 0, stream>>>(gl, ga, gv, csP, csN, hsN);

        // att1 MLP over cStar = [csP | csN]
        gemm(stream, 1, NB, HMLP, csP, TOTH, TOTH, csN, TOTH, TOTH,
             a1w1, ATTIN, a1w1 + TOTH, ATTIN, a1b1, nullptr, hid1, HMLP);
        gemm(stream, 0, NB, ATTIN, hid1, HMLP, HMLP, nullptr, 0, 0,
             a1w2, HMLP, nullptr, 0, a1b2, nullptr, lgts, ATTIN);

        softmax_attend<<<NB, 256, 0, stream>>>(lgts, csP, csN, attd);

        // att2: cHat = tanh(MLP2(attended))
        gemm(stream, 1, NB, HMLP, attd, ATTIN, ATTIN, nullptr, 0, 0,
             a2w1, ATTIN, nullptr, 0, a2b1, nullptr, hid2, HMLP);
        gemm(stream, 3, NB, MEMD, hid2, HMLP, HMLP, nullptr, 0, 0,
             a2w2, HMLP, nullptr, 0, a2b2, nullptr, chat, MEMD);

        // gamma1, gamma2 over both = [attended | mem]
        gemm(stream, 1, NB, HMLP, attd, ATTIN, ATTIN, memb, MEMD, MEMD,
             g1w1, GAMIN, g1w1 + ATTIN, GAMIN, g1b1, nullptr, hg1, HMLP);
        gemm(stream, 2, NB, MEMD, hg1, HMLP, HMLP, nullptr, 0, 0,
             g1w2, HMLP, nullptr, 0, g1b2, nullptr, gm1, MEMD);
        gemm(stream, 1, NB, HMLP, attd, ATTIN, ATTIN, memb, MEMD, MEMD,
             g2w1, GAMIN, g2w1 + ATTIN, GAMIN, g2b1, nullptr, hg2, HMLP);
        gemm(stream, 2, NB, MEMD, hg2, HMLP, HMLP, nullptr, 0, 0,
             g2w2, HMLP, nullptr, 0, g2b2, nullptr, gm2, MEMD);

        mem_update<<<(NB * MEMD + 255) / 256, 256, 0, stream>>>(memb, gm1, gm2, chat);
    }

    // final: out = MLP2([h_l,h_a,h_v,mem])  (final h is in hs0 after 64 steps)
    gemm(stream, 1, NB, HMLP, hs0, TOTH, TOTH, memb, MEMD, MEMD,
         ow1, FINAL_IN, ow1 + TOTH, FINAL_IN, ob1, nullptr, hout, HMLP);
    out_dot<<<NB / 4, 256, 0, stream>>>(hout, ow2, ob2, out);
}

// Round 2
// 12717.928 us; speedup vs baseline: 9.0261x; 9.0261x over previous
//
#include <hip/hip_runtime.h>
#include <hip/hip_bf16.h>

typedef unsigned short u16;
typedef unsigned int   u32;
typedef __attribute__((ext_vector_type(8))) short s16x8;   // 8 bf16 = 4 VGPRs
typedef __attribute__((ext_vector_type(4))) float f32x4;

// ---- problem constants ----
#define NB   1024
#define TT   64
#define DXL  300
#define DXA  74
#define DXV  35
#define DX   (DXL+DXA+DXV)   // 409
#define DHL  512
#define DHA  256
#define DHV  256
#define TOTH 1024
#define MEMD 512
#define HMLP 1024
#define ATTIN 2048
// padded x widths (multiples of 64)
#define PXL  320
#define PXA  128
#define PXV  64

__device__ __forceinline__ u16 f2b(float f) {
    union { float f; u32 u; } x; x.f = f;
    u32 r = x.u + 0x7fffu + ((x.u >> 16) & 1u);
    return (u16)(r >> 16);
}

__device__ __forceinline__ void gload_lds16(const void* g, void* l) {
    __builtin_amdgcn_global_load_lds(
        (const __attribute__((address_space(1))) unsigned int*)g,
        (__attribute__((address_space(3))) unsigned int*)l,
        16, 0, 0);
}

// ---------------------------------------------------------------------------
// bf16 MFMA NT GEMM:  C[m][n] = act( sum_k A[m][k] * W[n][k] + bias(n) )
// A composite: k < K0 -> A0 (lda0), else A1 (lda1).  W likewise.
// K0, K1 multiples of 64. M, Nout multiples of 64.
// 64x64 tile, BK=64, 256 threads = 4 waves (2x2), wave does 32x32 via
// 2x2 fragments of mfma_f32_16x16x32_bf16.
// LDS staged via global_load_lds (linear dest) with XOR chunk swizzle applied
// on the global source; ds_reads apply the same swizzle (rule #21).
// ---------------------------------------------------------------------------
template<int ACT, int OUT_BF16>   // ACT: 0 none 1 relu 2 sigmoid 3 tanh
__global__ __launch_bounds__(256) void gemm_mfma(
    const u16* __restrict__ A0, int lda0, int K0,
    const u16* __restrict__ A1, int lda1, int K1,
    const u16* __restrict__ W0, int ldw0,
    const u16* __restrict__ W1, int ldw1,
    const float* __restrict__ bias0, const float* __restrict__ bias1,
    void* __restrict__ C, int ldc)
{
    __shared__ u16 As[64 * 64];
    __shared__ u16 Bs[64 * 64];
    const int tid  = threadIdx.x;
    const int wid  = tid >> 6;
    const int lane = tid & 63;
    const int bm = blockIdx.y * 64;
    const int bn = blockIdx.x * 64;
    const int wr = wid >> 1, wc = wid & 1;

    f32x4 acc[2][2] = {};
    const int K = K0 + K1;

    for (int k0 = 0; k0 < K; k0 += 64) {
        const u16* Ap; int ldA, ka;
        const u16* Wp; int ldW, kw;
        if (k0 < K0) { Ap = A0; ldA = lda0; ka = k0;      Wp = W0; ldW = ldw0; kw = k0; }
        else         { Ap = A1; ldA = lda1; ka = k0 - K0; Wp = W1; ldW = ldw1; kw = k0 - K0; }

        #pragma unroll
        for (int i = 0; i < 2; ++i) {
            int e   = (wid * 2 + i) * 64 + lane;  // 0..511
            int row = e >> 3;                     // 0..63
            int p   = e & 7;                      // physical 16B chunk
            int c   = p ^ (row & 7);              // global (logical) chunk
            gload_lds16(Ap + (size_t)(bm + row) * ldA + ka + c * 8,
                        (char*)As + (wid * 2 + i) * 1024);
            gload_lds16(Wp + (size_t)(bn + row) * ldW + kw + c * 8,
                        (char*)Bs + (wid * 2 + i) * 1024);
        }
        __syncthreads();

        #pragma unroll
        for (int ks = 0; ks < 2; ++ks) {
            s16x8 af[2], bf[2];
            #pragma unroll
            for (int f = 0; f < 2; ++f) {
                int ra = wr * 32 + f * 16 + (lane & 15);
                int ca = ks * 4 + (lane >> 4);
                int pa = ca ^ (ra & 7);
                af[f] = *(const s16x8*)((const char*)As + ra * 128 + pa * 16);
                int rb = wc * 32 + f * 16 + (lane & 15);
                int pb = ca ^ (rb & 7);
                bf[f] = *(const s16x8*)((const char*)Bs + rb * 128 + pb * 16);
            }
            #pragma unroll
            for (int fi = 0; fi < 2; ++fi)
                #pragma unroll
                for (int fj = 0; fj < 2; ++fj)
                    acc[fi][fj] = __builtin_amdgcn_mfma_f32_16x16x32_bf16(
                        af[fi], bf[fj], acc[fi][fj], 0, 0, 0);
        }
        __syncthreads();
    }

    // epilogue: C/D layout col = lane&15, row = (lane>>4)*4 + reg   [m89-verified]
    #pragma unroll
    for (int fi = 0; fi < 2; ++fi)
        #pragma unroll
        for (int fj = 0; fj < 2; ++fj) {
            int col = bn + wc * 32 + fj * 16 + (lane & 15);
            float bia = bias0[col];
            if (bias1) bia += bias1[col];
            #pragma unroll
            for (int r4 = 0; r4 < 4; ++r4) {
                int row = bm + wr * 32 + fi * 16 + (lane >> 4) * 4 + r4;
                float v = acc[fi][fj][r4] + bia;
                if (ACT == 1) v = fmaxf(v, 0.f);
                else if (ACT == 2) v = 1.f / (1.f + __expf(-v));
                else if (ACT == 3) v = tanhf(v);
                if (OUT_BF16) ((u16*)C)[(size_t)row * ldc + col] = f2b(v);
                else          ((float*)C)[(size_t)row * ldc + col] = v;
            }
        }
}

// ---------------------------------------------------------------------------
// pointwise kernels
// ---------------------------------------------------------------------------
__global__ void lstm_pointwise(const float* __restrict__ gl,
                               const float* __restrict__ ga,
                               const float* __restrict__ gv,
                               const float* __restrict__ cs_prev,
                               float* __restrict__ cs_new,
                               u16* __restrict__ cs_new_b,
                               u16* __restrict__ hs_new_b)
{
    int idx = blockIdx.x * blockDim.x + threadIdx.x;
    if (idx >= NB * TOTH) return;
    int n = idx >> 10, u = idx & 1023;
    const float* g; int dh, gu;
    if (u < DHL)            { g = gl; dh = DHL; gu = u; }
    else if (u < DHL + DHA) { g = ga; dh = DHA; gu = u - DHL; }
    else                    { g = gv; dh = DHV; gu = u - DHL - DHA; }
    const float* grow = g + (size_t)n * 4 * dh;
    float gi = grow[gu], gf = grow[dh + gu], gg = grow[2 * dh + gu], go = grow[3 * dh + gu];
    float c  = cs_prev[idx];
    float si = 1.f / (1.f + __expf(-gi));
    float sf = 1.f / (1.f + __expf(-gf));
    float so = 1.f / (1.f + __expf(-go));
    float c2 = sf * c + si * tanhf(gg);
    float h2 = so * tanhf(c2);
    cs_new[idx]   = c2;
    cs_new_b[idx] = f2b(c2);
    hs_new_b[idx] = f2b(h2);
}

__global__ __launch_bounds__(256) void softmax_attend(
    const float* __restrict__ logits,
    const float* __restrict__ cs_prev,
    const float* __restrict__ cs_new,
    u16* __restrict__ attended_b)
{
    int n = blockIdx.x;
    const float* z = logits + (size_t)n * ATTIN;
    __shared__ float sred[4];
    int tid = threadIdx.x, lane = tid & 63, wid = tid >> 6;

    float m = -1e30f;
    for (int k = tid; k < ATTIN; k += 256) m = fmaxf(m, z[k]);
    #pragma unroll
    for (int off = 1; off < 64; off <<= 1) m = fmaxf(m, __shfl_xor(m, off));
    if (lane == 0) sred[wid] = m;
    __syncthreads();
    m = fmaxf(fmaxf(sred[0], sred[1]), fmaxf(sred[2], sred[3]));
    __syncthreads();

    float s = 0.f;
    for (int k = tid; k < ATTIN; k += 256) s += __expf(z[k] - m);
    #pragma unroll
    for (int off = 1; off < 64; off <<= 1) s += __shfl_xor(s, off);
    if (lane == 0) sred[wid] = s;
    __syncthreads();
    s = sred[0] + sred[1] + sred[2] + sred[3];
    float inv = 1.f / s;

    for (int k = tid; k < ATTIN; k += 256) {
        float cs = (k < TOTH) ? cs_prev[(size_t)n * TOTH + k]
                              : cs_new[(size_t)n * TOTH + (k - TOTH)];
        attended_b[(size_t)n * ATTIN + k] = f2b(__expf(z[k] - m) * inv * cs);
    }
}

__global__ void mem_update(float* __restrict__ memb,
                           u16* __restrict__ memb_b,
                           const float* __restrict__ g1,
                           const float* __restrict__ g2,
                           const float* __restrict__ chat)
{
    int idx = blockIdx.x * blockDim.x + threadIdx.x;
    if (idx >= NB * MEMD) return;
    float v = g1[idx] * memb[idx] + g2[idx] * chat[idx];
    memb[idx]   = v;
    memb_b[idx] = f2b(v);
}

__global__ __launch_bounds__(256) void out_dot(const float* __restrict__ hid,
                                               const float* __restrict__ w2,
                                               const float* __restrict__ b2,
                                               float* __restrict__ out)
{
    int wid = threadIdx.x >> 6, lane = threadIdx.x & 63;
    int n = blockIdx.x * 4 + wid;
    if (n >= NB) return;
    const float* h = hid + (size_t)n * HMLP;
    float s = 0.f;
    for (int k = lane; k < HMLP; k += 64) s += h[k] * w2[k];
    #pragma unroll
    for (int off = 1; off < 64; off <<= 1) s += __shfl_xor(s, off);
    if (lane == 0) out[n] = s + b2[0];
}

// convert fp32 (rows x ksrc) -> bf16 (rows x kdst), zero-padding cols >= ksrc
__global__ void cvt_pad(const float* __restrict__ src, u16* __restrict__ dst,
                        int rows, int ksrc, int kdst)
{
    int idx = blockIdx.x * blockDim.x + threadIdx.x;
    if (idx >= rows * kdst) return;
    int r = idx / kdst, c = idx - r * kdst;
    dst[idx] = f2b(c < ksrc ? src[(size_t)r * ksrc + c] : 0.f);
}

// per-step x conversion into 3 padded bf16 parts
__global__ void cvt_x(const float* __restrict__ X,
                      u16* __restrict__ xl, u16* __restrict__ xa, u16* __restrict__ xv,
                      int t)
{
    int idx = blockIdx.x * blockDim.x + threadIdx.x;   // NB * 512
    if (idx >= NB * 512) return;
    int n = idx >> 9, u = idx & 511;
    const float* row = X + ((size_t)t * NB + n) * DX;
    if (u < PXL)            xl[n * PXL + u]          = f2b(u < DXL ? row[u] : 0.f);
    else if (u < PXL + PXA) { int q = u - PXL;  xa[n * PXA + q] = f2b(q < DXA ? row[DXL + q] : 0.f); }
    else                    { int q = u - PXL - PXA; xv[n * PXV + q] = f2b(q < DXV ? row[DXL + DXA + q] : 0.f); }
}

__global__ void fill0(u32* __restrict__ p, int n)
{
    int i = blockIdx.x * blockDim.x + threadIdx.x;
    if (i < n) p[i] = 0u;
}

// ---------------------------------------------------------------------------
// host side
// ---------------------------------------------------------------------------
static void gemm(hipStream_t s, int act, int outbf, int M, int Nout,
                 const u16* A0, int lda0, int K0,
                 const u16* A1, int lda1, int K1,
                 const u16* W0, int ldw0, const u16* W1, int ldw1,
                 const float* b0, const float* b1, void* C, int ldc)
{
    dim3 g(Nout / 64, M / 64), b(256);
#define L(A, O) gemm_mfma<A, O><<<g, b, 0, s>>>(A0, lda0, K0, A1, lda1, K1, W0, ldw0, W1, ldw1, b0, b1, C, ldc)
    if (outbf) {
        switch (act) { case 0: L(0,1); break; case 1: L(1,1); break; case 2: L(2,1); break; default: L(3,1); break; }
    } else {
        switch (act) { case 0: L(0,0); break; case 1: L(1,0); break; case 2: L(2,0); break; default: L(3,0); break; }
    }
#undef L
}

extern "C" void kernel_launch(void* const* d_in, const int* in_sizes, int n_in,
                              void* d_out, int out_size, void* d_ws, size_t ws_size,
                              hipStream_t stream)
{
    const float* X     = (const float*)d_in[0];
    const float* Wih_l = (const float*)d_in[5];
    const float* Whh_l = (const float*)d_in[6];
    const float* bih_l = (const float*)d_in[7];
    const float* bhh_l = (const float*)d_in[8];
    const float* Wih_a = (const float*)d_in[9];
    const float* Whh_a = (const float*)d_in[10];
    const float* bih_a = (const float*)d_in[11];
    const float* bhh_a = (const float*)d_in[12];
    const float* Wih_v = (const float*)d_in[13];
    const float* Whh_v = (const float*)d_in[14];
    const float* bih_v = (const float*)d_in[15];
    const float* bhh_v = (const float*)d_in[16];
    const float* a1w1  = (const float*)d_in[17];
    const float* a1b1  = (const float*)d_in[18];
    const float* a1w2  = (const float*)d_in[19];
    const float* a1b2  = (const float*)d_in[20];
    const float* a2w1  = (const float*)d_in[21];
    const float* a2b1  = (const float*)d_in[22];
    const float* a2w2  = (const float*)d_in[23];
    const float* a2b2  = (const float*)d_in[24];
    const float* g1w1  = (const float*)d_in[25];
    const float* g1b1  = (const float*)d_in[26];
    const float* g1w2  = (const float*)d_in[27];
    const float* g1b2  = (const float*)d_in[28];
    const float* g2w1  = (const float*)d_in[29];
    const float* g2b1  = (const float*)d_in[30];
    const float* g2w2  = (const float*)d_in[31];
    const float* g2b2  = (const float*)d_in[32];
    const float* ow1   = (const float*)d_in[33];
    const float* ob1   = (const float*)d_in[34];
    const float* ow2   = (const float*)d_in[35];
    const float* ob2   = (const float*)d_in[36];
    float* out = (float*)d_out;

    // ---- workspace carve (256B aligned) ----
    char* wsp = (char*)d_ws;
    auto take = [&](size_t bytes) -> char* {
        char* r = wsp; wsp += (bytes + 255) & ~(size_t)255; return r;
    };
    // fp32 (cs0, cs1, memb contiguous for one zero-fill)
    float* cs0  = (float*)take((size_t)NB * TOTH * 4);
    float* cs1  = (float*)take((size_t)NB * TOTH * 4);
    float* memb = (float*)take((size_t)NB * MEMD * 4);
    float* gl   = (float*)take((size_t)NB * 2048 * 4);   // also reused as logits
    float* ga   = (float*)take((size_t)NB * 1024 * 4);
    float* gv   = (float*)take((size_t)NB * 1024 * 4);
    float* chat = (float*)take((size_t)NB * MEMD * 4);
    float* gm1  = (float*)take((size_t)NB * MEMD * 4);
    float* gm2  = (float*)take((size_t)NB * MEMD * 4);
    float* hout = (float*)take((size_t)NB * HMLP * 4);
    float* lgts = gl;
    // bf16 state (contiguous for one zero-fill): hs0b hs1b cs0b cs1b membb
    u16* hs0b  = (u16*)take((size_t)NB * TOTH * 2);
    u16* hs1b  = (u16*)take((size_t)NB * TOTH * 2);
    u16* cs0b  = (u16*)take((size_t)NB * TOTH * 2);
    u16* cs1b  = (u16*)take((size_t)NB * TOTH * 2);
    u16* membb = (u16*)take((size_t)NB * MEMD * 2);
    // bf16 transients
    u16* xlb   = (u16*)take((size_t)NB * PXL * 2);
    u16* xab   = (u16*)take((size_t)NB * PXA * 2);
    u16* xvb   = (u16*)take((size_t)NB * PXV * 2);
    u16* hid1b = (u16*)take((size_t)NB * HMLP * 2);
    u16* hid2b = (u16*)take((size_t)NB * HMLP * 2);
    u16* hg1b  = (u16*)take((size_t)NB * HMLP * 2);
    u16* hg2b  = (u16*)take((size_t)NB * HMLP * 2);
    u16* attdb = (u16*)take((size_t)NB * ATTIN * 2);
    // bf16 weights (K padded to x64 where needed)
    u16* wihlb = (u16*)take((size_t)2048 * PXL * 2);
    u16* whhlb = (u16*)take((size_t)2048 * DHL * 2);
    u16* wihab = (u16*)take((size_t)1024 * PXA * 2);
    u16* whhab = (u16*)take((size_t)1024 * DHA * 2);
    u16* wihvb = (u16*)take((size_t)1024 * PXV * 2);
    u16* whhvb = (u16*)take((size_t)1024 * DHV * 2);
    u16* a1w1b = (u16*)take((size_t)HMLP * ATTIN * 2);
    u16* a1w2b = (u16*)take((size_t)ATTIN * HMLP * 2);
    u16* a2w1b = (u16*)take((size_t)HMLP * ATTIN * 2);
    u16* a2w2b = (u16*)take((size_t)MEMD * HMLP * 2);
    u16* g1w1b = (u16*)take((size_t)HMLP * 2560 * 2);
    u16* g1w2b = (u16*)take((size_t)MEMD * HMLP * 2);
    u16* g2w1b = (u16*)take((size_t)HMLP * 2560 * 2);
    u16* g2w2b = (u16*)take((size_t)MEMD * HMLP * 2);
    u16* ow1b  = (u16*)take((size_t)HMLP * 1536 * 2);

    // ---- one-time per launch: zero state + convert weights to bf16 ----
    {
        int nf = NB * (TOTH * 2 + MEMD);            // fp32 words
        fill0<<<(nf + 255) / 256, 256, 0, stream>>>((u32*)cs0, nf);
        int nb = NB * (TOTH * 4 + MEMD) / 2;        // bf16 state as u32 words
        fill0<<<(nb + 255) / 256, 256, 0, stream>>>((u32*)hs0b, nb);
    }
    auto cvtw = [&](const float* src, u16* dst, int rows, int ksrc, int kdst) {
        int n = rows * kdst;
        cvt_pad<<<(n + 255) / 256, 256, 0, stream>>>(src, dst, rows, ksrc, kdst);
    };
    cvtw(Wih_l, wihlb, 2048, DXL, PXL);
    cvtw(Whh_l, whhlb, 2048, DHL, DHL);
    cvtw(Wih_a, wihab, 1024, DXA, PXA);
    cvtw(Whh_a, whhab, 1024, DHA, DHA);
    cvtw(Wih_v, wihvb, 1024, DXV, PXV);
    cvtw(Whh_v, whhvb, 1024, DHV, DHV);
    cvtw(a1w1, a1w1b, HMLP, ATTIN, ATTIN);
    cvtw(a1w2, a1w2b, ATTIN, HMLP, HMLP);
    cvtw(a2w1, a2w1b, HMLP, ATTIN, ATTIN);
    cvtw(a2w2, a2w2b, MEMD, HMLP, HMLP);
    cvtw(g1w1, g1w1b, HMLP, 2560, 2560);
    cvtw(g1w2, g1w2b, MEMD, HMLP, HMLP);
    cvtw(g2w1, g2w1b, HMLP, 2560, 2560);
    cvtw(g2w2, g2w2b, MEMD, HMLP, HMLP);
    cvtw(ow1,  ow1b,  HMLP, 1536, 1536);

    float* csf[2] = { cs0, cs1 };
    u16*   csb[2] = { cs0b, cs1b };
    u16*   hsb[2] = { hs0b, hs1b };

    for (int t = 0; t < TT; ++t) {
        float* csP = csf[t & 1];       float* csN = csf[(t + 1) & 1];
        u16* csPb = csb[t & 1];        u16* csNb = csb[(t + 1) & 1];
        u16* hsPb = hsb[t & 1];        u16* hsNb = hsb[(t + 1) & 1];

        cvt_x<<<(NB * 512 + 255) / 256, 256, 0, stream>>>(X, xlb, xab, xvb, t);

        // LSTM gates: [x_t | h] @ [Wih | Whh]^T + bih + bhh
        gemm(stream, 0, 0, NB, 4 * DHL, xlb, PXL, PXL, hsPb, TOTH, DHL,
             wihlb, PXL, whhlb, DHL, bih_l, bhh_l, gl, 4 * DHL);
        gemm(stream, 0, 0, NB, 4 * DHA, xab, PXA, PXA, hsPb + DHL, TOTH, DHA,
             wihab, PXA, whhab, DHA, bih_a, bhh_a, ga, 4 * DHA);
        gemm(stream, 0, 0, NB, 4 * DHV, xvb, PXV, PXV, hsPb + DHL + DHA, TOTH, DHV,
             wihvb, PXV, whhvb, DHV, bih_v, bhh_v, gv, 4 * DHV);

        lstm_pointwise<<<(NB * TOTH + 255) / 256, 256, 0, stream>>>(
            gl, ga, gv, csP, csN, csNb, hsNb);

        // att1: relu(cStar @ w1^T + b1) @ w2^T + b2 ; cStar = [csP | csN]
        gemm(stream, 1, 1, NB, HMLP, csPb, TOTH, TOTH, csNb, TOTH, TOTH,
             a1w1b, ATTIN, a1w1b + TOTH, ATTIN, a1b1, nullptr, hid1b, HMLP);
        gemm(stream, 0, 0, NB, ATTIN, hid1b, HMLP, HMLP, nullptr, 0, 0,
             a1w2b, HMLP, nullptr, 0, a1b2, nullptr, lgts, ATTIN);

        softmax_attend<<<NB, 256, 0, stream>>>(lgts, csP, csN, attdb);

        // att2: cHat = tanh(MLP2(attended))
        gemm(stream, 1, 1, NB, HMLP, attdb, ATTIN, ATTIN, nullptr, 0, 0,
             a2w1b, ATTIN, nullptr, 0, a2b1, nullptr, hid2b, HMLP);
        gemm(stream, 3, 0, NB, MEMD, hid2b, HMLP, HMLP, nullptr, 0, 0,
             a2w2b, HMLP, nullptr, 0, a2b2, nullptr, chat, MEMD);

        // gamma1 / gamma2 over both = [attended | mem]
        gemm(stream, 1, 1, NB, HMLP, attdb, ATTIN, ATTIN, membb, MEMD, MEMD,
             g1w1b, 2560, g1w1b + ATTIN, 2560, g1b1, nullptr, hg1b, HMLP);
        gemm(stream, 2, 0, NB, MEMD, hg1b, HMLP, HMLP, nullptr, 0, 0,
             g1w2b, HMLP, nullptr, 0, g1b2, nullptr, gm1, MEMD);
        gemm(stream, 1, 1, NB, HMLP, attdb, ATTIN, ATTIN, membb, MEMD, MEMD,
             g2w1b, 2560, g2w1b + ATTIN, 2560, g2b1, nullptr, hg2b, HMLP);
        gemm(stream, 2, 0, NB, MEMD, hg2b, HMLP, HMLP, nullptr, 0, 0,
             g2w2b, HMLP, nullptr, 0, g2b2, nullptr, gm2, MEMD);

        mem_update<<<(NB * MEMD + 255) / 256, 256, 0, stream>>>(memb, membb, gm1, gm2, chat);
    }

    // final: out = relu([h | mem] @ ow1^T + ob1) @ ow2^T + ob2
    gemm(stream, 1, 0, NB, HMLP, hsb[0], TOTH, TOTH, membb, MEMD, MEMD,
         ow1b, 1536, ow1b + TOTH, 1536, ob1, nullptr, hout, HMLP);
    out_dot<<<NB / 4, 256, 0, stream>>>(hout, ow2, ob2, out);
}

// Round 3
// 7755.157 us; speedup vs baseline: 14.8022x; 1.6399x over previous
//
#include <hip/hip_runtime.h>
#include <hip/hip_bf16.h>

typedef unsigned short u16;
typedef unsigned int   u32;
typedef __attribute__((ext_vector_type(8))) short s16x8;   // 8 bf16 = 4 VGPRs
typedef __attribute__((ext_vector_type(4))) float f32x4;

// ---- problem constants ----
#define NB   1024
#define TT   64
#define DXL  300
#define DXA  74
#define DXV  35
#define DX   (DXL+DXA+DXV)   // 409
#define DHL  512
#define DHA  256
#define DHV  256
#define TOTH 1024
#define MEMD 512
#define HMLP 1024
#define ATTIN 2048
// padded x widths (multiples of 64)
#define PXL  320
#define PXA  128
#define PXV  64

__device__ __forceinline__ u16 f2b(float f) {
    union { float f; u32 u; } x; x.f = f;
    u32 r = x.u + 0x7fffu + ((x.u >> 16) & 1u);
    return (u16)(r >> 16);
}

__device__ __forceinline__ void gload_lds16(const void* g, void* l) {
    __builtin_amdgcn_global_load_lds(
        (const __attribute__((address_space(1))) unsigned int*)g,
        (__attribute__((address_space(3))) unsigned int*)l,
        16, 0, 0);
}

// ---------------------------------------------------------------------------
// Grouped bf16 MFMA NT GEMM: up to 3 independent problems per launch, routed
// by blockIdx.x range. Each problem: C[m][n] = act(sum_k A[m][k]*W[n][k]+bias)
// A/W composite in k (k<K0 -> *0, else *1). All dims multiples of 64; M=1024.
// 64x64 tile, BK=64, 4 waves (2x2 of 32x32), double-buffered LDS staging via
// global_load_lds with XOR chunk swizzle (pre-swizzled source + swizzled read).
// ---------------------------------------------------------------------------
struct GP {
    const u16* A0; const u16* A1; const u16* W0; const u16* W1;
    const float* b0; const float* b1; void* C;
    int lda0, K0, lda1, K1, ldw0, ldw1, ldc, act, outbf, bStart, gx;
};

__global__ __launch_bounds__(256) void gemm_group(GP p0, GP p1, GP p2)
{
    __shared__ u16 As[2][64 * 64];
    __shared__ u16 Bs[2][64 * 64];
    GP p;
    {
        int bx = blockIdx.x;
        if (bx < p1.bStart) p = p0;
        else if (bx < p2.bStart) p = p1;
        else p = p2;
    }
    const int tid  = threadIdx.x;
    const int wid  = tid >> 6;
    const int lane = tid & 63;
    const int bm = blockIdx.y * 64;
    const int bn = (blockIdx.x - p.bStart) * 64;
    const int wr = wid >> 1, wc = wid & 1;
    const int nt = (p.K0 + p.K1) >> 6;
    const int e0 = wid * 2 * 64 + lane;

    auto stage = [&](int t, int buf) {
        int k0 = t << 6;
        const u16 *Ap, *Wp; int ldA, ldW, ka;
        if (k0 < p.K0) { Ap = p.A0; ldA = p.lda0; ka = k0;        Wp = p.W0; ldW = p.ldw0; }
        else           { Ap = p.A1; ldA = p.lda1; ka = k0 - p.K0; Wp = p.W1; ldW = p.ldw1; }
        #pragma unroll
        for (int i = 0; i < 2; ++i) {
            int e   = e0 + i * 64;
            int row = e >> 3;                 // 0..63
            int c   = (e & 7) ^ (row & 7);    // logical 16B chunk (inverse swizzle on source)
            gload_lds16(Ap + (size_t)(bm + row) * ldA + ka + c * 8,
                        (char*)&As[buf][0] + (wid * 2 + i) * 1024);
            gload_lds16(Wp + (size_t)(bn + row) * ldW + ka + c * 8,
                        (char*)&Bs[buf][0] + (wid * 2 + i) * 1024);
        }
    };

    f32x4 acc[2][2] = {};
    stage(0, 0);
    __syncthreads();

    for (int t = 0; t < nt; ++t) {
        if (t + 1 < nt) stage(t + 1, (t + 1) & 1);
        const char* Ab = (const char*)&As[t & 1][0];
        const char* Bb = (const char*)&Bs[t & 1][0];
        #pragma unroll
        for (int ks = 0; ks < 2; ++ks) {
            s16x8 af[2], bf[2];
            #pragma unroll
            for (int f = 0; f < 2; ++f) {
                int ra = wr * 32 + f * 16 + (lane & 15);
                int ca = ks * 4 + (lane >> 4);
                af[f] = *(const s16x8*)(Ab + ra * 128 + (ca ^ (ra & 7)) * 16);
                int rb = wc * 32 + f * 16 + (lane & 15);
                bf[f] = *(const s16x8*)(Bb + rb * 128 + (ca ^ (rb & 7)) * 16);
            }
            #pragma unroll
            for (int fi = 0; fi < 2; ++fi)
                #pragma unroll
                for (int fj = 0; fj < 2; ++fj)
                    acc[fi][fj] = __builtin_amdgcn_mfma_f32_16x16x32_bf16(
                        af[fi], bf[fj], acc[fi][fj], 0, 0, 0);
        }
        __syncthreads();   // drains this wave's vmcnt (prefetch) + lgkm, then barrier
    }

    // epilogue: C/D layout col = lane&15, row = (lane>>4)*4 + reg  [m89-verified]
    #pragma unroll
    for (int fi = 0; fi < 2; ++fi)
        #pragma unroll
        for (int fj = 0; fj < 2; ++fj) {
            int col = bn + wc * 32 + fj * 16 + (lane & 15);
            float bia = p.b0[col];
            if (p.b1) bia += p.b1[col];
            #pragma unroll
            for (int r4 = 0; r4 < 4; ++r4) {
                int row = bm + wr * 32 + fi * 16 + (lane >> 4) * 4 + r4;
                float v = acc[fi][fj][r4] + bia;
                if (p.act == 1)      v = fmaxf(v, 0.f);
                else if (p.act == 2) v = 1.f / (1.f + __expf(-v));
                else if (p.act == 3) v = tanhf(v);
                if (p.outbf) ((u16*)p.C)[(size_t)row * p.ldc + col] = f2b(v);
                else         ((float*)p.C)[(size_t)row * p.ldc + col] = v;
            }
        }
}

// ---------------------------------------------------------------------------
// pointwise kernels
// ---------------------------------------------------------------------------
// LSTM pointwise + fused x-conversion for step tnext.
__global__ void lstm_pointwise(const float* __restrict__ gl,
                               const float* __restrict__ ga,
                               const float* __restrict__ gv,
                               const float* __restrict__ cs_prev,
                               float* __restrict__ cs_new,
                               u16* __restrict__ cs_new_b,
                               u16* __restrict__ hs_new_b,
                               const float* __restrict__ X, int tnext,
                               u16* __restrict__ xl, u16* __restrict__ xa,
                               u16* __restrict__ xv)
{
    int idx = blockIdx.x * blockDim.x + threadIdx.x;
    if (idx >= NB * TOTH) return;
    int n = idx >> 10, u = idx & 1023;
    const float* g; int dh, gu;
    if (u < DHL)            { g = gl; dh = DHL; gu = u; }
    else if (u < DHL + DHA) { g = ga; dh = DHA; gu = u - DHL; }
    else                    { g = gv; dh = DHV; gu = u - DHL - DHA; }
    const float* grow = g + (size_t)n * 4 * dh;
    float gi = grow[gu], gf = grow[dh + gu], gg = grow[2 * dh + gu], go = grow[3 * dh + gu];
    float c  = cs_prev[idx];
    float si = 1.f / (1.f + __expf(-gi));
    float sf = 1.f / (1.f + __expf(-gf));
    float so = 1.f / (1.f + __expf(-go));
    float c2 = sf * c + si * tanhf(gg);
    float h2 = so * tanhf(c2);
    cs_new[idx]   = c2;
    cs_new_b[idx] = f2b(c2);
    hs_new_b[idx] = f2b(h2);

    // fused conversion of x for step tnext (half the threads)
    if (tnext < TT && u < 512) {
        const float* row = X + ((size_t)tnext * NB + n) * DX;
        if (u < PXL)            xl[n * PXL + u] = f2b(u < DXL ? row[u] : 0.f);
        else if (u < PXL + PXA) { int q = u - PXL;       xa[n * PXA + q] = f2b(q < DXA ? row[DXL + q] : 0.f); }
        else                    { int q = u - PXL - PXA; xv[n * PXV + q] = f2b(q < DXV ? row[DXL + DXA + q] : 0.f); }
    }
}

// softmax + attend, with previous step's mem-update fused in front.
__global__ __launch_bounds__(256) void softmax_attend(
    const float* __restrict__ logits,
    const float* __restrict__ cs_prev,
    const float* __restrict__ cs_new,
    u16* __restrict__ attended_b,
    int do_mem,
    float* __restrict__ memb, u16* __restrict__ membb,
    const float* __restrict__ g1, const float* __restrict__ g2,
    const float* __restrict__ chat)
{
    int n = blockIdx.x;
    int tid = threadIdx.x, lane = tid & 63, wid = tid >> 6;

    if (do_mem) {
        for (int k = tid; k < MEMD; k += 256) {
            size_t i = (size_t)n * MEMD + k;
            float v = g1[i] * memb[i] + g2[i] * chat[i];
            memb[i]  = v;
            membb[i] = f2b(v);
        }
    }

    const float* z = logits + (size_t)n * ATTIN;
    __shared__ float sred[4];

    float m = -1e30f;
    for (int k = tid; k < ATTIN; k += 256) m = fmaxf(m, z[k]);
    #pragma unroll
    for (int off = 1; off < 64; off <<= 1) m = fmaxf(m, __shfl_xor(m, off));
    if (lane == 0) sred[wid] = m;
    __syncthreads();
    m = fmaxf(fmaxf(sred[0], sred[1]), fmaxf(sred[2], sred[3]));
    __syncthreads();

    float s = 0.f;
    for (int k = tid; k < ATTIN; k += 256) s += __expf(z[k] - m);
    #pragma unroll
    for (int off = 1; off < 64; off <<= 1) s += __shfl_xor(s, off);
    if (lane == 0) sred[wid] = s;
    __syncthreads();
    s = sred[0] + sred[1] + sred[2] + sred[3];
    float inv = 1.f / s;

    for (int k = tid; k < ATTIN; k += 256) {
        float cs = (k < TOTH) ? cs_prev[(size_t)n * TOTH + k]
                              : cs_new[(size_t)n * TOTH + (k - TOTH)];
        attended_b[(size_t)n * ATTIN + k] = f2b(__expf(z[k] - m) * inv * cs);
    }
}

__global__ void mem_update(float* __restrict__ memb,
                           u16* __restrict__ memb_b,
                           const float* __restrict__ g1,
                           const float* __restrict__ g2,
                           const float* __restrict__ chat)
{
    int idx = blockIdx.x * blockDim.x + threadIdx.x;
    if (idx >= NB * MEMD) return;
    float v = g1[idx] * memb[idx] + g2[idx] * chat[idx];
    memb[idx]   = v;
    memb_b[idx] = f2b(v);
}

__global__ __launch_bounds__(256) void out_dot(const float* __restrict__ hid,
                                               const float* __restrict__ w2,
                                               const float* __restrict__ b2,
                                               float* __restrict__ out)
{
    int wid = threadIdx.x >> 6, lane = threadIdx.x & 63;
    int n = blockIdx.x * 4 + wid;
    if (n >= NB) return;
    const float* h = hid + (size_t)n * HMLP;
    float s = 0.f;
    for (int k = lane; k < HMLP; k += 64) s += h[k] * w2[k];
    #pragma unroll
    for (int off = 1; off < 64; off <<= 1) s += __shfl_xor(s, off);
    if (lane == 0) out[n] = s + b2[0];
}

// initial x conversion (t=0 only)
__global__ void cvt_x(const float* __restrict__ X,
                      u16* __restrict__ xl, u16* __restrict__ xa, u16* __restrict__ xv,
                      int t)
{
    int idx = blockIdx.x * blockDim.x + threadIdx.x;   // NB * 512
    if (idx >= NB * 512) return;
    int n = idx >> 9, u = idx & 511;
    const float* row = X + ((size_t)t * NB + n) * DX;
    if (u < PXL)            xl[n * PXL + u] = f2b(u < DXL ? row[u] : 0.f);
    else if (u < PXL + PXA) { int q = u - PXL;       xa[n * PXA + q] = f2b(q < DXA ? row[DXL + q] : 0.f); }
    else                    { int q = u - PXL - PXA; xv[n * PXV + q] = f2b(q < DXV ? row[DXL + DXA + q] : 0.f); }
}

// grouped weight conversion: 15 fp32->bf16 (optionally k-padded) conversions
#define NWC 15
struct WDesc { const float* src; u16* dst; int rows, ksrc, kdst, bstart; };
struct WPack { WDesc d[NWC]; };

__global__ __launch_bounds__(256) void wcvt_all(WPack wp)
{
    int bx = blockIdx.x;
    int di = 0;
    #pragma unroll
    for (int i = 1; i < NWC; ++i) if (bx >= wp.d[i].bstart) di = i;
    WDesc d = wp.d[di];
    int n = d.rows * d.kdst;
    int base = (bx - d.bstart) * 2048 + threadIdx.x;
    if (d.ksrc == d.kdst) {
        #pragma unroll
        for (int j = 0; j < 8; ++j) {
            int idx = base + j * 256;
            if (idx < n) d.dst[idx] = f2b(d.src[idx]);
        }
    } else {
        #pragma unroll
        for (int j = 0; j < 8; ++j) {
            int idx = base + j * 256;
            if (idx < n) {
                int r = idx / d.kdst, c = idx - r * d.kdst;
                d.dst[idx] = f2b(c < d.ksrc ? d.src[(size_t)r * d.ksrc + c] : 0.f);
            }
        }
    }
}

__global__ void fill0(u32* __restrict__ p, int n)
{
    int i = blockIdx.x * blockDim.x + threadIdx.x;
    if (i < n) p[i] = 0u;
}

// ---------------------------------------------------------------------------
// host side
// ---------------------------------------------------------------------------
static GP mkgp(const u16* A0, int lda0, int K0, const u16* A1, int lda1, int K1,
               const u16* W0, int ldw0, const u16* W1, int ldw1,
               const float* b0, const float* b1, void* C, int ldc,
               int Nout, int act, int outbf)
{
    GP p;
    p.A0 = A0; p.A1 = A1; p.W0 = W0; p.W1 = W1; p.b0 = b0; p.b1 = b1; p.C = C;
    p.lda0 = lda0; p.K0 = K0; p.lda1 = lda1; p.K1 = K1;
    p.ldw0 = ldw0; p.ldw1 = ldw1; p.ldc = ldc; p.act = act; p.outbf = outbf;
    p.bStart = 0; p.gx = Nout / 64;
    return p;
}

static void launch_group(hipStream_t s, GP* p, int np)
{
    int total = 0;
    for (int i = 0; i < np; ++i) { p[i].bStart = total; total += p[i].gx; }
    GP dummy = {};
    dummy.bStart = 0x7fffffff;
    GP p1 = (np > 1) ? p[1] : dummy;
    GP p2 = (np > 2) ? p[2] : dummy;
    gemm_group<<<dim3(total, 16), 256, 0, s>>>(p[0], p1, p2);
}

extern "C" void kernel_launch(void* const* d_in, const int* in_sizes, int n_in,
                              void* d_out, int out_size, void* d_ws, size_t ws_size,
                              hipStream_t stream)
{
    const float* X     = (const float*)d_in[0];
    const float* Wih_l = (const float*)d_in[5];
    const float* Whh_l = (const float*)d_in[6];
    const float* bih_l = (const float*)d_in[7];
    const float* bhh_l = (const float*)d_in[8];
    const float* Wih_a = (const float*)d_in[9];
    const float* Whh_a = (const float*)d_in[10];
    const float* bih_a = (const float*)d_in[11];
    const float* bhh_a = (const float*)d_in[12];
    const float* Wih_v = (const float*)d_in[13];
    const float* Whh_v = (const float*)d_in[14];
    const float* bih_v = (const float*)d_in[15];
    const float* bhh_v = (const float*)d_in[16];
    const float* a1w1  = (const float*)d_in[17];
    const float* a1b1  = (const float*)d_in[18];
    const float* a1w2  = (const float*)d_in[19];
    const float* a1b2  = (const float*)d_in[20];
    const float* a2w1  = (const float*)d_in[21];
    const float* a2b1  = (const float*)d_in[22];
    const float* a2w2  = (const float*)d_in[23];
    const float* a2b2  = (const float*)d_in[24];
    const float* g1w1  = (const float*)d_in[25];
    const float* g1b1  = (const float*)d_in[26];
    const float* g1w2  = (const float*)d_in[27];
    const float* g1b2  = (const float*)d_in[28];
    const float* g2w1  = (const float*)d_in[29];
    const float* g2b1  = (const float*)d_in[30];
    const float* g2w2  = (const float*)d_in[31];
    const float* g2b2  = (const float*)d_in[32];
    const float* ow1   = (const float*)d_in[33];
    const float* ob1   = (const float*)d_in[34];
    const float* ow2   = (const float*)d_in[35];
    const float* ob2   = (const float*)d_in[36];
    float* out = (float*)d_out;

    // ---- workspace carve (256B aligned) ----
    char* wsp = (char*)d_ws;
    auto take = [&](size_t bytes) -> char* {
        char* r = wsp; wsp += (bytes + 255) & ~(size_t)255; return r;
    };
    float* cs0  = (float*)take((size_t)NB * TOTH * 4);
    float* cs1  = (float*)take((size_t)NB * TOTH * 4);
    float* memb = (float*)take((size_t)NB * MEMD * 4);
    float* gl   = (float*)take((size_t)NB * 2048 * 4);   // reused as logits
    float* ga   = (float*)take((size_t)NB * 1024 * 4);
    float* gv   = (float*)take((size_t)NB * 1024 * 4);
    float* chat = (float*)take((size_t)NB * MEMD * 4);
    float* gm1  = (float*)take((size_t)NB * MEMD * 4);
    float* gm2  = (float*)take((size_t)NB * MEMD * 4);
    float* hout = (float*)take((size_t)NB * HMLP * 4);
    float* lgts = gl;
    u16* hs0b  = (u16*)take((size_t)NB * TOTH * 2);
    u16* hs1b  = (u16*)take((size_t)NB * TOTH * 2);
    u16* cs0b  = (u16*)take((size_t)NB * TOTH * 2);
    u16* cs1b  = (u16*)take((size_t)NB * TOTH * 2);
    u16* membb = (u16*)take((size_t)NB * MEMD * 2);
    u16* xlb   = (u16*)take((size_t)NB * PXL * 2);
    u16* xab   = (u16*)take((size_t)NB * PXA * 2);
    u16* xvb   = (u16*)take((size_t)NB * PXV * 2);
    u16* hid1b = (u16*)take((size_t)NB * HMLP * 2);
    u16* hid2b = (u16*)take((size_t)NB * HMLP * 2);
    u16* hg1b  = (u16*)take((size_t)NB * HMLP * 2);
    u16* hg2b  = (u16*)take((size_t)NB * HMLP * 2);
    u16* attdb = (u16*)take((size_t)NB * ATTIN * 2);
    u16* wihlb = (u16*)take((size_t)2048 * PXL * 2);
    u16* whhlb = (u16*)take((size_t)2048 * DHL * 2);
    u16* wihab = (u16*)take((size_t)1024 * PXA * 2);
    u16* whhab = (u16*)take((size_t)1024 * DHA * 2);
    u16* wihvb = (u16*)take((size_t)1024 * PXV * 2);
    u16* whhvb = (u16*)take((size_t)1024 * DHV * 2);
    u16* a1w1b = (u16*)take((size_t)HMLP * ATTIN * 2);
    u16* a1w2b = (u16*)take((size_t)ATTIN * HMLP * 2);
    u16* a2w1b = (u16*)take((size_t)HMLP * ATTIN * 2);
    u16* a2w2b = (u16*)take((size_t)MEMD * HMLP * 2);
    u16* g1w1b = (u16*)take((size_t)HMLP * 2560 * 2);
    u16* g1w2b = (u16*)take((size_t)MEMD * HMLP * 2);
    u16* g2w1b = (u16*)take((size_t)HMLP * 2560 * 2);
    u16* g2w2b = (u16*)take((size_t)MEMD * HMLP * 2);
    u16* ow1b  = (u16*)take((size_t)HMLP * 1536 * 2);

    // ---- prologue: zero state, grouped weight conversion, x(0) conversion ----
    {
        int nf = NB * (TOTH * 2 + MEMD);
        fill0<<<(nf + 255) / 256, 256, 0, stream>>>((u32*)cs0, nf);
        int nb = NB * (TOTH * 4 + MEMD) / 2;
        fill0<<<(nb + 255) / 256, 256, 0, stream>>>((u32*)hs0b, nb);
    }
    {
        WPack wp;
        const float* src[NWC] = { Wih_l, Whh_l, Wih_a, Whh_a, Wih_v, Whh_v,
                                  a1w1, a1w2, a2w1, a2w2, g1w1, g1w2, g2w1, g2w2, ow1 };
        u16* dst[NWC] = { wihlb, whhlb, wihab, whhab, wihvb, whhvb,
                          a1w1b, a1w2b, a2w1b, a2w2b, g1w1b, g1w2b, g2w1b, g2w2b, ow1b };
        int rows[NWC] = { 2048, 2048, 1024, 1024, 1024, 1024,
                          HMLP, ATTIN, HMLP, MEMD, HMLP, MEMD, HMLP, MEMD, HMLP };
        int ksrc[NWC] = { DXL, DHL, DXA, DHA, DXV, DHV,
                          ATTIN, HMLP, ATTIN, HMLP, 2560, HMLP, 2560, HMLP, 1536 };
        int kdst[NWC] = { PXL, DHL, PXA, DHA, PXV, DHV,
                          ATTIN, HMLP, ATTIN, HMLP, 2560, HMLP, 2560, HMLP, 1536 };
        int total = 0;
        for (int i = 0; i < NWC; ++i) {
            wp.d[i].src = src[i]; wp.d[i].dst = dst[i];
            wp.d[i].rows = rows[i]; wp.d[i].ksrc = ksrc[i]; wp.d[i].kdst = kdst[i];
            wp.d[i].bstart = total;
            total += (rows[i] * kdst[i] + 2047) / 2048;
        }
        wcvt_all<<<total, 256, 0, stream>>>(wp);
    }
    cvt_x<<<(NB * 512 + 255) / 256, 256, 0, stream>>>(X, xlb, xab, xvb, 0);

    float* csf[2] = { cs0, cs1 };
    u16*   csb[2] = { cs0b, cs1b };
    u16*   hsb[2] = { hs0b, hs1b };

    for (int t = 0; t < TT; ++t) {
        float* csP = csf[t & 1];  float* csN = csf[(t + 1) & 1];
        u16* csPb = csb[t & 1];   u16* csNb = csb[(t + 1) & 1];
        u16* hsPb = hsb[t & 1];   u16* hsNb = hsb[(t + 1) & 1];

        // 1) LSTM gate GEMMs (grouped x3)
        {
            GP ps[3] = {
                mkgp(xlb, PXL, PXL, hsPb, TOTH, DHL,
                     wihlb, PXL, whhlb, DHL, bih_l, bhh_l, gl, 4 * DHL, 4 * DHL, 0, 0),
                mkgp(xab, PXA, PXA, hsPb + DHL, TOTH, DHA,
                     wihab, PXA, whhab, DHA, bih_a, bhh_a, ga, 4 * DHA, 4 * DHA, 0, 0),
                mkgp(xvb, PXV, PXV, hsPb + DHL + DHA, TOTH, DHV,
                     wihvb, PXV, whhvb, DHV, bih_v, bhh_v, gv, 4 * DHV, 4 * DHV, 0, 0) };
            launch_group(stream, ps, 3);
        }

        // 2) LSTM pointwise + x(t+1) conversion
        lstm_pointwise<<<(NB * TOTH + 255) / 256, 256, 0, stream>>>(
            gl, ga, gv, csP, csN, csNb, hsNb, X, t + 1, xlb, xab, xvb);

        // 3) att1 layer 1
        {
            GP ps[1] = { mkgp(csPb, TOTH, TOTH, csNb, TOTH, TOTH,
                              a1w1b, ATTIN, a1w1b + TOTH, ATTIN, a1b1, nullptr,
                              hid1b, HMLP, HMLP, 1, 1) };
            launch_group(stream, ps, 1);
        }
        // 4) att1 layer 2 (logits)
        {
            GP ps[1] = { mkgp(hid1b, HMLP, HMLP, nullptr, 0, 0,
                              a1w2b, HMLP, nullptr, 0, a1b2, nullptr,
                              lgts, ATTIN, ATTIN, 0, 0) };
            launch_group(stream, ps, 1);
        }

        // 5) softmax+attend (+ previous step's mem update)
        softmax_attend<<<NB, 256, 0, stream>>>(lgts, csP, csN, attdb,
                                               t > 0 ? 1 : 0, memb, membb, gm1, gm2, chat);

        // 6) grouped L1: att2-L1, g1-L1, g2-L1
        {
            GP ps[3] = {
                mkgp(attdb, ATTIN, ATTIN, nullptr, 0, 0,
                     a2w1b, ATTIN, nullptr, 0, a2b1, nullptr, hid2b, HMLP, HMLP, 1, 1),
                mkgp(attdb, ATTIN, ATTIN, membb, MEMD, MEMD,
                     g1w1b, 2560, g1w1b + ATTIN, 2560, g1b1, nullptr, hg1b, HMLP, HMLP, 1, 1),
                mkgp(attdb, ATTIN, ATTIN, membb, MEMD, MEMD,
                     g2w1b, 2560, g2w1b + ATTIN, 2560, g2b1, nullptr, hg2b, HMLP, HMLP, 1, 1) };
            launch_group(stream, ps, 3);
        }
        // 7) grouped L2: att2-L2(tanh), g1-L2(sig), g2-L2(sig)
        {
            GP ps[3] = {
                mkgp(hid2b, HMLP, HMLP, nullptr, 0, 0,
                     a2w2b, HMLP, nullptr, 0, a2b2, nullptr, chat, MEMD, MEMD, 3, 0),
                mkgp(hg1b, HMLP, HMLP, nullptr, 0, 0,
                     g1w2b, HMLP, nullptr, 0, g1b2, nullptr, gm1, MEMD, MEMD, 2, 0),
                mkgp(hg2b, HMLP, HMLP, nullptr, 0, 0,
                     g2w2b, HMLP, nullptr, 0, g2b2, nullptr, gm2, MEMD, MEMD, 2, 0) };
            launch_group(stream, ps, 3);
        }
    }

    // final mem update (step 63)
    mem_update<<<(NB * MEMD + 255) / 256, 256, 0, stream>>>(memb, membb, gm1, gm2, chat);

    // final: out = relu([h | mem] @ ow1^T + ob1) @ ow2^T + ob2
    {
        GP ps[1] = { mkgp(hsb[0], TOTH, TOTH, membb, MEMD, MEMD,
                          ow1b, 1536, ow1b + TOTH, 1536, ob1, nullptr,
                          hout, HMLP, HMLP, 1, 0) };
        launch_group(stream, ps, 1);
    }
    out_dot<<<NB / 4, 256, 0, stream>>>(hout, ow2, ob2, out);
}